// Round 21
// baseline (239.133 us; speedup 1.0000x reference)
//
#include <hip/hip_runtime.h>

typedef unsigned int u32;
typedef unsigned short u16;
typedef float f32x4_t  __attribute__((ext_vector_type(4)));
typedef float f32x16_t __attribute__((ext_vector_type(16)));
typedef u32   u32x4_t  __attribute__((ext_vector_type(4)));
typedef __bf16 bf16x8_t __attribute__((ext_vector_type(8)));
typedef __bf16 bf16x2_t __attribute__((ext_vector_type(2)));

#define B_   8
#define S_   8192
#define D_   1024
#define KSEL 1024

// ---------------- workspace layout (bytes) ----------------
#define OFF_WQ   0ul                      // 128*1024 bf16 (pre-scaled by 0.125)
#define OFF_WKV  (256ul<<10)              // 192*1024 bf16 row-major
#define OFF_WO   (640ul<<10)              // 1024*64 bf16
#define OFF_TIDX (768ul<<10)              // 8*1024 int
#define OFF_K1   (1ul<<20)                // [B][S][64] bf16 = 8MB
#define OFF_K2   (OFF_K1 + (8ul<<20))
#define OFF_V    (OFF_K2 + (8ul<<20))
#define OFF_Q1   (OFF_V  + (8ul<<20))     // [B][K][64] bf16 = 1MB
#define OFF_Q2   (OFF_Q1 + (1ul<<20))
#define OFF_PST  (OFF_Q2 + (1ul<<20))     // [B][32][8][2] records of 4608B = 18.9MB

#define PREC 2304   // pst record stride in u16: 2048 O-bf16 + 128 (m f32) + 128 (l f32)

static __device__ __forceinline__ u16 f2bf(float f){
  return __builtin_bit_cast(u16, (__bf16)f);
}
static __device__ __forceinline__ float bf2f(u16 v){
  u32 u = ((u32)v)<<16; return __builtin_bit_cast(float, u);
}
static __device__ __forceinline__ u32 pkbf(float a, float b){
  bf16x2_t v; v[0] = (__bf16)a; v[1] = (__bf16)b;
  return __builtin_bit_cast(u32, v);
}
static __device__ __forceinline__ f32x16_t zero16(){
  f32x16_t z;
  #pragma unroll
  for (int i=0;i<16;i++) z[i]=0.f;
  return z;
}
static __device__ __forceinline__ bf16x8_t bc8(u32x4_t v){ return __builtin_bit_cast(bf16x8_t, v); }
static __device__ __forceinline__ f32x16_t mfma32(bf16x8_t a, bf16x8_t b, f32x16_t c){
  return __builtin_amdgcn_mfma_f32_32x32x16_bf16(a,b,c,0,0,0);
}
static __device__ __forceinline__ f32x4_t mfma16(bf16x8_t a, bf16x8_t b, f32x4_t c){
  return __builtin_amdgcn_mfma_f32_16x16x32_bf16(a,b,c,0,0,0);
}
static __device__ __forceinline__ void gl_lds16(const void* g, void* l){
  __builtin_amdgcn_global_load_lds((const __attribute__((address_space(1))) u32*)g,
                                   (__attribute__((address_space(3))) u32*)l, 16, 0, 0);
}

// ---------------- fused prep (weights->bf16) + exact top-K (parallel scan) ----------------
__global__ __launch_bounds__(256) void preptopk_kernel(const float* __restrict__ wq,
                                                       const float* __restrict__ wkv,
                                                       const float* __restrict__ wo,
                                                       const float* __restrict__ imp,
                                                       u16* owq, u16* owkv, u16* owo,
                                                       int* __restrict__ tidx){
  if (blockIdx.x >= 8){
    const int i = (blockIdx.x-8)*256 + threadIdx.x;
    if (i < 128*1024) owq[i]  = f2bf(wq[i] * 0.125f);   // fold 1/sqrt(64)
    if (i < 192*1024) owkv[i] = f2bf(wkv[i]);
    if (i < 64*1024)  owo[i]  = f2bf(wo[i]);
    return;
  }
  const int b = blockIdx.x, t = threadIdx.x;
  __shared__ u32 hist[256];
  __shared__ u32 sscan[256];
  __shared__ u32 shPrefix;
  __shared__ int shNeed;
  __shared__ u32 cnt2, eqc;
  __shared__ int eqlist[256];
  u32 key[32];
  const float* ip = imp + (long)b*S_;
  #pragma unroll
  for (int i=0;i<32;i++){
    u32 u = __builtin_bit_cast(u32, ip[t + 256*i]);
    key[i] = (u & 0x80000000u) ? ~u : (u | 0x80000000u);  // order-preserving map
  }
  if (t==0){ shPrefix = 0; shNeed = KSEL; cnt2 = 0; eqc = 0; }
  for (int pass=0; pass<4; ++pass){
    const int shift = 24 - 8*pass;
    __syncthreads();
    hist[t] = 0;
    __syncthreads();
    const u32 pfx = shPrefix;
    const int need = shNeed;
    #pragma unroll
    for (int i=0;i<32;i++){
      bool act = (pass==0) || ((key[i] >> (shift+8)) == pfx);
      if (act) atomicAdd(&hist[(key[i]>>shift)&255u], 1u);
    }
    __syncthreads();
    // parallel suffix scan: sscan[t] = sum_{j>=t} hist[j]
    sscan[t] = hist[t];
    __syncthreads();
    for (int off=1; off<256; off<<=1){
      const u32 v = (t+off < 256) ? sscan[t+off] : 0u;
      __syncthreads();
      sscan[t] += v;
      __syncthreads();
    }
    const u32 un = (u32)need;
    const u32 s_t  = sscan[t];
    const u32 s_t1 = (t<255) ? sscan[t+1] : 0u;
    if (s_t >= un && s_t1 < un){
      shPrefix = (pfx<<8) | (u32)t;
      shNeed = need - (int)s_t1;
    }
  }
  __syncthreads();
  const u32 T = shPrefix; const int needEq = shNeed;
  #pragma unroll
  for (int i=0;i<32;i++){
    const int s = t + 256*i;
    if (key[i] > T){ u32 p = atomicAdd(&cnt2,1u); tidx[b*KSEL + p] = s; }
    else if (key[i] == T){ u32 e = atomicAdd(&eqc,1u); if (e < 256u) eqlist[e] = s; }
  }
  __syncthreads();
  if (t==0){
    int n = (int)eqc; if (n > 256) n = 256;
    const int bpos = (int)cnt2;
    for (int j=0;j<needEq && j<n;j++){
      int mi = j;
      for (int k2=j+1;k2<n;k2++) if (eqlist[k2] < eqlist[mi]) mi = k2;
      int tmp = eqlist[j]; eqlist[j]=eqlist[mi]; eqlist[mi]=tmp;
      tidx[b*KSEL + bpos + j] = eqlist[j];
    }
  }
}

// ---------------- fused q GEMM (blocks 0..255) + kv GEMM (blocks 256..767) ----------------
// qgemm first: gen-1 pairs 1 qgemm + 1 kv per CU (r19, best measured).
// kv role: deferred out-store (r17).
__global__ __launch_bounds__(256,2) void kvq_kernel(const float* __restrict__ x,
                                                    const u16* __restrict__ wkv,
                                                    const u16* __restrict__ wq,
                                                    const int* __restrict__ tidx,
                                                    u16* __restrict__ K1, u16* __restrict__ K2, u16* __restrict__ V,
                                                    u16* __restrict__ Q1, u16* __restrict__ Q2,
                                                    float* __restrict__ out){
  __shared__ __align__(16) char smem[81920];
  const int tid = threadIdx.x;
  const int w = tid>>6, lane = tid&63, lo4 = lane&15, hi = lane>>4;

  if (blockIdx.x >= 256){
    // ================= kv role =================
    char* lA0 = smem;            // 2 x 16KB
    char* lB0 = smem + 32768;    // 2 x 24KB
    const long row0 = (long)(blockIdx.x - 256) * 128;
    const int srow8 = tid>>4;   // 0..15
    const int cseg  = tid&15;   // 0..15
    const float* xp = x   + (row0 + srow8)*1024 + cseg*4;
    float*       op = out + (row0 + srow8)*1024 + cseg*4;
    f32x4_t acc[12][2];
    #pragma unroll
    for (int i=0;i<12;i++){ acc[i][0]=(f32x4_t){0,0,0,0}; acc[i][1]=(f32x4_t){0,0,0,0}; }
    f32x4_t f[8], fp[8];

    auto LOADX = [&](int k0){
      #pragma unroll
      for (int i=0;i<8;i++) f[i] = *(const f32x4_t*)(xp + k0 + i*16*1024);
    };
    auto OUTSTORE = [&](int k0){     // deferred out-store of the PREVIOUS tile
      #pragma unroll
      for (int i=0;i<8;i++)
        *(f32x4_t*)(op + k0 + i*16*1024) = fp[i];
    };
    auto LDSWRITE = [&](int buf){    // bf16 pack + swizzled LDS write from f[]
      #pragma unroll
      for (int i=0;i<8;i++){
        const u32 row = (u32)(srow8 + i*16);
        u32 byte = row*128u + (u32)cseg*8u;
        byte ^= (row&7u)<<4;
        uint2 p; p.x = pkbf(f[i][0], f[i][1]); p.y = pkbf(f[i][2], f[i][3]);
        *(uint2*)(lA0 + buf*16384 + byte) = p;
      }
    };
    auto SAVEF = [&](){
      #pragma unroll
      for (int i=0;i<8;i++) fp[i] = f[i];
    };
    auto STAGEB = [&](int buf, int k0){
      #pragma unroll
      for (int ii=0; ii<6; ++ii){
        const int inst = w*6 + ii;
        const u32 L = (u32)inst*1024u + (u32)lane*16u;
        const u32 n = L>>7, off = L&127u;
        const char* src = (const char*)wkv + (size_t)n*2048 + (size_t)k0*2 + (off ^ ((n&7u)<<4));
        gl_lds16(src, lB0 + buf*24576 + (size_t)inst*1024);
      }
    };

    LOADX(0); STAGEB(0, 0); LDSWRITE(0); SAVEF();
    __syncthreads();

    for (int t=0; t<16; ++t){
      const int cur = t&1, nxt = cur^1;
      OUTSTORE(t*64);                             // store tile t (loaded last iter) early
      if (t < 15){ LOADX((t+1)*64); STAGEB(nxt, (t+1)*64); }
      #pragma unroll
      for (int kk=0;kk<2;kk++){
        bf16x8_t xf[2];
        #pragma unroll
        for (int ns=0;ns<2;ns++){
          const int s = w*32 + ns*16 + lo4;
          u32 byte = ((u32)s<<7) + ((u32)kk<<6) + ((u32)hi<<4); byte ^= ((u32)(s&7))<<4;
          xf[ns] = *(const bf16x8_t*)(lA0 + cur*16384 + byte);
        }
        #pragma unroll
        for (int ms=0;ms<12;ms++){
          const int e = ms*16 + lo4;
          u32 byte = ((u32)e<<7) + ((u32)kk<<6) + ((u32)hi<<4); byte ^= ((u32)(e&7))<<4;
          const bf16x8_t wf = *(const bf16x8_t*)(lB0 + cur*24576 + byte);
          acc[ms][0] = mfma16(wf, xf[0], acc[ms][0]);
          acc[ms][1] = mfma16(wf, xf[1], acc[ms][1]);
        }
      }
      if (t < 15){ LDSWRITE(nxt); SAVEF(); }
      __syncthreads();
    }

    #pragma unroll
    for (int ms=0;ms<12;ms++){
      const int e0 = ms*16 + 4*hi;
      const int arr = e0>>6, eh = e0&63;
      u16* basep = arr==0 ? K1 : (arr==1 ? K2 : V);
      #pragma unroll
      for (int ns=0;ns<2;ns++){
        const long srow = row0 + w*32 + ns*16 + lo4;
        ushort4 v;
        v.x = f2bf(acc[ms][ns][0]); v.y = f2bf(acc[ms][ns][1]);
        v.z = f2bf(acc[ms][ns][2]); v.w = f2bf(acc[ms][ns][3]);
        *(ushort4*)(basep + srow*64 + eh) = v;
      }
    }
  } else {
    // ================= qgemm role (blocks 0..255, dispatched first) =================
    u16* lW   = (u16*)smem;              // 16KB
    u16* lX   = (u16*)(smem + 16384);    // 4KB
    int* rows = (int*)(smem + 20480);    // 128B
    const int bq = blockIdx.x;
    const int b = bq >> 5, q0 = (bq & 31) * 32;
    if (tid < 32) rows[tid] = tidx[b*KSEL + q0 + tid];
    __syncthreads();
    const int sq = tid>>3, qt8 = tid&7;
    const float* xp = x + ((long)b*S_ + rows[sq])*1024 + qt8*8;
    f32x4_t acc[2][2];
    #pragma unroll
    for (int i=0;i<2;i++){ acc[i][0]=(f32x4_t){0,0,0,0}; acc[i][1]=(f32x4_t){0,0,0,0}; }

    for (int k0=0;k0<1024;k0+=64){
      __syncthreads();
      f32x4_t f0 = *(const f32x4_t*)(xp + k0);
      f32x4_t f1 = *(const f32x4_t*)(xp + k0 + 4);
      {
        const u32 byte = ((u32)sq<<7) + ((u32)(qt8 ^ (sq&7))<<4);
        *(u32x4_t*)((char*)lX + byte) =
          (u32x4_t){pkbf(f0[0],f0[1]), pkbf(f0[2],f0[3]), pkbf(f1[0],f1[1]), pkbf(f1[2],f1[3])};
      }
      #pragma unroll
      for (int ii=0; ii<4; ++ii){
        const int inst = w*4 + ii;
        const u32 L = (u32)inst*1024u + (u32)lane*16u;
        const u32 n = L>>7, off = L&127u;
        const char* src = (const char*)wq + (size_t)n*2048 + (size_t)k0*2 + (off ^ ((n&7u)<<4));
        gl_lds16(src, (char*)lW + (size_t)inst*1024);
      }
      __syncthreads();
      #pragma unroll
      for (int kk=0;kk<2;kk++){
        bf16x8_t xf[2];
        #pragma unroll
        for (int ns=0;ns<2;ns++){
          const int s = ns*16 + lo4;
          u32 byte = ((u32)s<<7) + ((u32)kk<<6) + ((u32)hi<<4); byte ^= ((u32)(s&7))<<4;
          xf[ns] = *(const bf16x8_t*)((const char*)lX + byte);
        }
        #pragma unroll
        for (int ms=0;ms<2;ms++){
          const int e = w*32 + ms*16 + lo4;
          u32 byte = ((u32)e<<7) + ((u32)kk<<6) + ((u32)hi<<4); byte ^= ((u32)(e&7))<<4;
          const bf16x8_t wf = *(const bf16x8_t*)((const char*)lW + byte);
          acc[ms][0] = mfma16(wf, xf[0], acc[ms][0]);
          acc[ms][1] = mfma16(wf, xf[1], acc[ms][1]);
        }
      }
    }
    #pragma unroll
    for (int ms=0;ms<2;ms++){
      const int e0 = w*32 + ms*16 + 4*hi;
      const int arr = e0>>6, eh = e0&63;
      u16* basep = arr ? Q2 : Q1;
      #pragma unroll
      for (int ns=0;ns<2;ns++){
        const int qg = q0 + ns*16 + lo4;
        ushort4 v;
        v.x = f2bf(acc[ms][ns][0]); v.y = f2bf(acc[ms][ns][1]);
        v.z = f2bf(acc[ms][ns][2]); v.w = f2bf(acc[ms][ns][3]);
        *(ushort4*)(basep + ((long)b*KSEL + qg)*64 + eh) = v;
      }
    }
  }
}

// ---------------- flash attention (dual head, swapped QK^T, S split 8, defer-max) ----------------
// T14 on V (r20) + double-buffered K tiles: K glds for tile it+1 are issued
// during compute(it) into the inactive buffer, draining for free at the next
// iteration's barrier A (was: issued after A, drained at B with only the
// short V-write phase as cover). LDS 25KB -> 41KB, still 2 blocks/CU.
__global__ __launch_bounds__(256,2) void attn_kernel(
    const u16* __restrict__ Q1g, const u16* __restrict__ Q2g,
    const u16* __restrict__ K1g, const u16* __restrict__ K2g,
    const u16* __restrict__ Vg,  u16* __restrict__ pst)
{
  __shared__ __align__(16) u16 lK1[2][64*64];
  __shared__ __align__(16) u16 lK2[2][64*64];
  __shared__ __align__(16) u16 lVT[64*64];
  const int tid = threadIdx.x;
  const int w = tid>>6, lane = tid&63;
  const int lo5 = lane&31, hi = lane>>5;
  const int b  = blockIdx.x>>6;
  const int qt = (blockIdx.x>>3)&7;
  const int c  = blockIdx.x&7;
  const int qw = qt*4 + w;
  const int qg = qw*32 + lo5;

  u32x4_t qf[2][4];
  {
    const u16* q1p = Q1g + ((long)b*KSEL + qg)*64;
    const u16* q2p = Q2g + ((long)b*KSEL + qg)*64;
    #pragma unroll
    for (int ks=0;ks<4;ks++){
      qf[0][ks] = *(const u32x4_t*)(q1p + ks*16 + hi*8);
      qf[1][ks] = *(const u32x4_t*)(q2p + ks*16 + hi*8);
    }
  }
  f32x16_t O00 = zero16(), O01 = zero16(), O10 = zero16(), O11 = zero16();
  float m0v = -INFINITY, m1v = -INFINITY, l0v = 0.f, l1v = 0.f;
  const int vkey2 = (tid&31)*2, vdg8 = tid>>5;   // key pair + d octet

  auto KSTAGE = [&](int it, int buf){
    const int s0 = c*1024 + it*64;
    #pragma unroll
    for (int ii=0; ii<2; ++ii){
      const int inst = w*2 + ii;
      const u32 L = (u32)inst*1024u + (u32)lane*16u;
      const u32 r = L>>7;
      const u32 so = (r<<7) | ((L&127u) ^ ((r&7u)<<4));
      const long gb = ((long)(b*S_ + s0))*128;
      gl_lds16((const char*)K1g + gb + so, (char*)lK1[buf] + (size_t)inst*1024);
      gl_lds16((const char*)K2g + gb + so, (char*)lK2[buf] + (size_t)inst*1024);
    }
  };

  // prologue: K glds(0) into buf 0, V regs(0)
  KSTAGE(0, 0);
  u32x4_t va0, va1;
  {
    const u16* vp0 = Vg + ((long)(b*S_ + c*1024 + vkey2))*64 + vdg8*8;
    va0 = *(const u32x4_t*)(vp0);
    va1 = *(const u32x4_t*)(vp0 + 64);
  }

  for (int it=0; it<16; ++it){
    const int kbuf = it&1;
    const int s0 = c*1024 + it*64;
    __syncthreads();                               // A: K glds(it) drained (issued last compute)
    // stage V transposed (V^T[d][key]) from registers loaded last iteration
    {
      #pragma unroll
      for (int j=0;j<8;j++){
        const u32 w0 = va0[j>>1], w1 = va1[j>>1];
        const u16 v0 = (j&1) ? (u16)(w0>>16) : (u16)(w0 & 0xffffu);
        const u16 v1 = (j&1) ? (u16)(w1>>16) : (u16)(w1 & 0xffffu);
        const int d = vdg8*8 + j;
        u32 byte = ((u32)d<<7) + (u32)vkey2*2;
        byte ^= ((u32)(d&7))<<4;
        *(u32*)((char*)lVT + byte) = (u32)v0 | ((u32)v1<<16);
      }
    }
    __syncthreads();                               // B: staging visible
    // T14/T3: issue next tile's K glds (inactive buffer) + V reg loads now;
    // they ride during compute and drain at the next barrier A.
    if (it < 15){
      KSTAGE(it+1, kbuf^1);
      const u16* vpn = Vg + ((long)(b*S_ + s0 + 64 + vkey2))*64 + vdg8*8;
      va0 = *(const u32x4_t*)(vpn);
      va1 = *(const u32x4_t*)(vpn + 64);
    }
    #pragma unroll
    for (int h=0; h<2; ++h){
      const u16* lK = h ? lK2[kbuf] : lK1[kbuf];
      f32x16_t sc0 = zero16(), sc1 = zero16();   // D[key][q]: col=q, rows=keys
      #pragma unroll
      for (int ks=0; ks<4; ++ks){
        u32 byteA = (((u32)lo5)<<7) + ((u32)ks<<5) + ((u32)hi<<4);
        byteA ^= ((u32)(lo5&7))<<4;
        const bf16x8_t kf0 = *(const bf16x8_t*)((const char*)lK + byteA);
        const bf16x8_t kf1 = *(const bf16x8_t*)((const char*)lK + (byteA + 4096));
        sc0 = mfma32(kf0, bc8(qf[h][ks]), sc0);
        sc1 = mfma32(kf1, bc8(qf[h][ks]), sc1);
      }
      const float mref = h ? m1v : m0v;
      float tmax = -INFINITY;
      #pragma unroll
      for (int i=0;i<16;i++){ tmax = fmaxf(tmax, sc0[i]); tmax = fmaxf(tmax, sc1[i]); }
      tmax = fmaxf(tmax, __shfl_xor(tmax, 32, 64));
      // defer-max: only advance m when tile max exceeds m_old + 8 (P <= e^8)
      const bool upd = (tmax > mref + 8.f);
      const float mnew = upd ? tmax : mref;
      const float ce = upd ? __expf(mref - mnew) : 1.f;
      float lsum = 0.f;
      #pragma unroll
      for (int i=0;i<16;i++){
        sc0[i] = __expf(sc0[i]-mnew); lsum += sc0[i];
        sc1[i] = __expf(sc1[i]-mnew); lsum += sc1[i];
      }
      lsum += __shfl_xor(lsum, 32, 64);
      if (h==0){ l0v = upd ? l0v*ce + lsum : l0v + lsum; m0v = mnew; }
      else     { l1v = upd ? l1v*ce + lsum : l1v + lsum; m1v = mnew; }
      f32x16_t &Oa = h ? O10 : O00;
      f32x16_t &Ob = h ? O11 : O01;
      if (upd){
        #pragma unroll
        for (int i=0;i<16;i++){ Oa[i] *= ce; Ob[i] *= ce; }
      }
      #pragma unroll
      for (int kb=0; kb<2; ++kb){
        const f32x16_t &s = kb ? sc1 : sc0;
        u32 pk[8], sx[8];
        #pragma unroll
        for (int i=0;i<8;i++) pk[i] = pkbf(s[2*i], s[2*i+1]);
        #pragma unroll
        for (int i=0;i<8;i++) sx[i] = (u32)__shfl_xor((int)pk[i], 32, 64);
        #pragma unroll
        for (int dd=0; dd<2; ++dd){
          const u32 w0 = hi ? sx[4*dd+2] : pk[4*dd];
          const u32 w1 = hi ? sx[4*dd+3] : pk[4*dd+1];
          const u32 w2 = hi ? pk[4*dd+2] : sx[4*dd];
          const u32 w3 = hi ? pk[4*dd+3] : sx[4*dd+1];
          const bf16x8_t pf = bc8((u32x4_t){w0,w1,w2,w3});
          const int ksG = kb*2 + dd;
          u32 byteV = (((u32)lo5)<<7) + ((u32)ksG<<5) + ((u32)hi<<4);
          byteV ^= ((u32)(lo5&7))<<4;
          const bf16x8_t vf0 = *(const bf16x8_t*)((const char*)lVT + byteV);
          const bf16x8_t vf1 = *(const bf16x8_t*)((const char*)lVT + (byteV + 4096));
          Oa = mfma32(vf0, pf, Oa);
          Ob = mfma32(vf1, pf, Ob);
        }
      }
    }
  }
  const long rec = (((long)b*32 + qw)*8 + c)*2;
  u16* p0 = pst + rec*PREC;
  u16* p1 = p0 + PREC;
  #pragma unroll
  for (int r2=0;r2<16;r2++){
    p0[(   r2)*64 + lane] = f2bf(O00[r2]);
    p0[(16+r2)*64 + lane] = f2bf(O01[r2]);
    p1[(   r2)*64 + lane] = f2bf(O10[r2]);
    p1[(16+r2)*64 + lane] = f2bf(O11[r2]);
  }
  ((float*)(p0+2048))[lane] = m0v; ((float*)(p0+2176))[lane] = l0v;
  ((float*)(p1+2048))[lane] = m1v; ((float*)(p1+2176))[lane] = l1v;
}

// ---------------- combine chunks + RMS + W_out GEMM + merge + scatter ----------------
__global__ __launch_bounds__(64,1) void combine_kernel(
    const u16* __restrict__ pst, const int* __restrict__ tidx,
    const float* __restrict__ x, const float* __restrict__ rmsw,
    const float* __restrict__ lamp, const float* __restrict__ gatep,
    const u16* __restrict__ wo, const float* __restrict__ bo,
    float* __restrict__ out)
{
  const int lane = threadIdx.x, lo5 = lane&31, hi = lane>>5;
  const int sb = blockIdx.x & 3;
  const int qw = (blockIdx.x>>2) & 31;
  const int b  = blockIdx.x >> 7;
  const float lam = 1.f/(1.f + __expf(-lamp[0]));
  const float g = gatep[0];
  const long rec0 = ((long)b*32 + qw)*16;
  float att[2][16];
  #pragma unroll
  for (int h=0; h<2; ++h){
    const u16* ph = pst + (rec0 + h)*PREC;
    float mc[8], lc[8];
    float mm = -INFINITY;
    #pragma unroll
    for (int cc=0;cc<8;cc++){
      const u16* pc = ph + (size_t)cc*2*PREC;
      mc[cc] = ((const float*)(pc+2048))[lane];
      lc[cc] = ((const float*)(pc+2176))[lane];
      mm = fmaxf(mm, mc[cc]);
    }
    float ef[8]; float L = 0.f;
    #pragma unroll
    for (int cc=0;cc<8;cc++){ ef[cc] = __expf(mc[cc]-mm); L += lc[cc]*ef[cc]; }
    const float invL = 1.f/L;
    #pragma unroll
    for (int dB=0; dB<2; ++dB){
      #pragma unroll
      for (int r=0;r<16;r++){
        float o = 0.f;
        #pragma unroll
        for (int cc=0;cc<8;cc++)
          o += ef[cc]*bf2f(ph[(size_t)cc*2*PREC + (dB*16+r)*64 + lane]);
        o *= invL;
        if (h==0) att[dB][r] = o; else att[dB][r] -= lam*o;
      }
    }
  }
  float ss = 0.f;
  #pragma unroll
  for (int dB=0;dB<2;dB++)
    #pragma unroll
    for (int r=0;r<16;r++) ss += att[dB][r]*att[dB][r];
  ss += __shfl_xor(ss, 32, 64);
  const float inv = rsqrtf(ss*(1.0f/64.0f) + 1e-6f);
  #pragma unroll
  for (int dB=0;dB<2;dB++){
    #pragma unroll
    for (int rq=0;rq<4;rq++){
      const f32x4_t wv = *(const f32x4_t*)(rmsw + dB*32 + 8*rq + 4*hi);
      #pragma unroll
      for (int j=0;j<4;j++) att[dB][4*rq+j] *= inv*wv[j];
    }
  }
  bf16x8_t hf[4];
  #pragma unroll
  for (int dB=0;dB<2;dB++){
    u32 pk[8], sx[8];
    #pragma unroll
    for (int i=0;i<8;i++) pk[i] = pkbf(att[dB][2*i], att[dB][2*i+1]);
    #pragma unroll
    for (int i=0;i<8;i++) sx[i] = (u32)__shfl_xor((int)pk[i], 32, 64);
    #pragma unroll
    for (int dd=0; dd<2; ++dd){
      const u32 w0 = hi ? sx[4*dd+2] : pk[4*dd];
      const u32 w1 = hi ? sx[4*dd+3] : pk[4*dd+1];
      const u32 w2 = hi ? pk[4*dd+2] : sx[4*dd];
      const u32 w3 = hi ? pk[4*dd+3] : sx[4*dd+1];
      hf[dB*2+dd] = bc8((u32x4_t){w0,w1,w2,w3});
    }
  }
  const int srow = tidx[b*KSEL + qw*32 + lo5];
  const float* xr  = x   + ((long)b*S_ + srow)*1024;
  float*       orr = out + ((long)b*S_ + srow)*1024;
  for (int st=sb*8; st<sb*8+8; ++st){
    f32x16_t acc = zero16();
    #pragma unroll
    for (int ks=0;ks<4;ks++){
      const u32x4_t wq4 = *(const u32x4_t*)(wo + ((long)(st*32 + lo5))*64 + ks*16 + hi*8);
      acc = mfma32(bc8(wq4), hf[ks], acc);
    }
    #pragma unroll
    for (int rq=0;rq<4;rq++){
      const int d0 = st*32 + 8*rq + 4*hi;
      const f32x4_t bo4 = *(const f32x4_t*)(bo + d0);
      const f32x4_t xv  = *(const f32x4_t*)(xr + d0);
      f32x4_t mg;
      #pragma unroll
      for (int j=0;j<4;j++){
        const float y = acc[4*rq+j] + bo4[j];
        mg[j] = g*y + (1.f-g)*xv[j];
      }
      *(f32x4_t*)(orr + d0) = mg;
    }
  }
}

// ---------------- launcher ----------------
extern "C" void kernel_launch(void* const* d_in, const int* in_sizes, int n_in,
                              void* d_out, int out_size, void* d_ws, size_t ws_size,
                              hipStream_t stream) {
  (void)in_sizes; (void)n_in; (void)out_size; (void)ws_size;
  const float* x    = (const float*)d_in[0];
  const float* imp  = (const float*)d_in[1];
  const float* wq   = (const float*)d_in[2];
  const float* wkv  = (const float*)d_in[3];
  const float* lamp = (const float*)d_in[4];
  const float* rmsw = (const float*)d_in[5];
  const float* gate = (const float*)d_in[6];
  const float* wo   = (const float*)d_in[7];
  const float* bo   = (const float*)d_in[8];
  float* out = (float*)d_out;
  char* ws = (char*)d_ws;
  u16* Wq   = (u16*)(ws + OFF_WQ);
  u16* Wkv  = (u16*)(ws + OFF_WKV);
  u16* Wo   = (u16*)(ws + OFF_WO);
  int* Tidx = (int*)(ws + OFF_TIDX);
  u16* K1   = (u16*)(ws + OFF_K1);
  u16* K2   = (u16*)(ws + OFF_K2);
  u16* V    = (u16*)(ws + OFF_V);
  u16* Q1   = (u16*)(ws + OFF_Q1);
  u16* Q2   = (u16*)(ws + OFF_Q2);
  u16* Pst  = (u16*)(ws + OFF_PST);

  preptopk_kernel<<<776, 256, 0, stream>>>(wq, wkv, wo, imp, Wq, Wkv, Wo, Tidx);
  kvq_kernel<<<768, 256, 0, stream>>>(x, Wkv, Wq, Tidx, K1, K2, V, Q1, Q2, out);
  attn_kernel<<<512, 256, 0, stream>>>(Q1, Q2, K1, K2, V, Pst);
  combine_kernel<<<1024, 64, 0, stream>>>(Pst, Tidx, x, rmsw, lamp, gate, Wo, bo, out);
}

// Round 22
// 238.822 us; speedup vs baseline: 1.0013x; 1.0013x over previous
//
#include <hip/hip_runtime.h>

typedef unsigned int u32;
typedef unsigned short u16;
typedef float f32x4_t  __attribute__((ext_vector_type(4)));
typedef float f32x16_t __attribute__((ext_vector_type(16)));
typedef u32   u32x4_t  __attribute__((ext_vector_type(4)));
typedef __bf16 bf16x8_t __attribute__((ext_vector_type(8)));
typedef __bf16 bf16x2_t __attribute__((ext_vector_type(2)));

#define B_   8
#define S_   8192
#define D_   1024
#define KSEL 1024

// ---------------- workspace layout (bytes) ----------------
#define OFF_WQ   0ul                      // 128*1024 bf16 (pre-scaled by 0.125)
#define OFF_WKV  (256ul<<10)              // 192*1024 bf16 row-major
#define OFF_WO   (640ul<<10)              // 1024*64 bf16
#define OFF_TIDX (768ul<<10)              // 8*1024 int
#define OFF_K1   (1ul<<20)                // [B][S][64] bf16 = 8MB
#define OFF_K2   (OFF_K1 + (8ul<<20))
#define OFF_V    (OFF_K2 + (8ul<<20))
#define OFF_Q1   (OFF_V  + (8ul<<20))     // [B][K][64] bf16 = 1MB
#define OFF_Q2   (OFF_Q1 + (1ul<<20))
#define OFF_PST  (OFF_Q2 + (1ul<<20))     // [B][32][8][2] records of 4608B = 18.9MB

#define PREC 2304   // pst record stride in u16: 2048 O-bf16 + 128 (m f32) + 128 (l f32)

static __device__ __forceinline__ u16 f2bf(float f){
  return __builtin_bit_cast(u16, (__bf16)f);
}
static __device__ __forceinline__ float bf2f(u16 v){
  u32 u = ((u32)v)<<16; return __builtin_bit_cast(float, u);
}
static __device__ __forceinline__ u32 pkbf(float a, float b){
  bf16x2_t v; v[0] = (__bf16)a; v[1] = (__bf16)b;
  return __builtin_bit_cast(u32, v);
}
static __device__ __forceinline__ f32x16_t zero16(){
  f32x16_t z;
  #pragma unroll
  for (int i=0;i<16;i++) z[i]=0.f;
  return z;
}
static __device__ __forceinline__ bf16x8_t bc8(u32x4_t v){ return __builtin_bit_cast(bf16x8_t, v); }
static __device__ __forceinline__ f32x16_t mfma32(bf16x8_t a, bf16x8_t b, f32x16_t c){
  return __builtin_amdgcn_mfma_f32_32x32x16_bf16(a,b,c,0,0,0);
}
static __device__ __forceinline__ f32x4_t mfma16(bf16x8_t a, bf16x8_t b, f32x4_t c){
  return __builtin_amdgcn_mfma_f32_16x16x32_bf16(a,b,c,0,0,0);
}
static __device__ __forceinline__ void gl_lds16(const void* g, void* l){
  __builtin_amdgcn_global_load_lds((const __attribute__((address_space(1))) u32*)g,
                                   (__attribute__((address_space(3))) u32*)l, 16, 0, 0);
}

// ---------------- fused prep (weights->bf16) + exact top-K (parallel scan) ----------------
__global__ __launch_bounds__(256) void preptopk_kernel(const float* __restrict__ wq,
                                                       const float* __restrict__ wkv,
                                                       const float* __restrict__ wo,
                                                       const float* __restrict__ imp,
                                                       u16* owq, u16* owkv, u16* owo,
                                                       int* __restrict__ tidx){
  if (blockIdx.x >= 8){
    const int i = (blockIdx.x-8)*256 + threadIdx.x;
    if (i < 128*1024) owq[i]  = f2bf(wq[i] * 0.125f);   // fold 1/sqrt(64)
    if (i < 192*1024) owkv[i] = f2bf(wkv[i]);
    if (i < 64*1024)  owo[i]  = f2bf(wo[i]);
    return;
  }
  const int b = blockIdx.x, t = threadIdx.x;
  __shared__ u32 hist[256];
  __shared__ u32 sscan[256];
  __shared__ u32 shPrefix;
  __shared__ int shNeed;
  __shared__ u32 cnt2, eqc;
  __shared__ int eqlist[256];
  u32 key[32];
  const float* ip = imp + (long)b*S_;
  #pragma unroll
  for (int i=0;i<32;i++){
    u32 u = __builtin_bit_cast(u32, ip[t + 256*i]);
    key[i] = (u & 0x80000000u) ? ~u : (u | 0x80000000u);  // order-preserving map
  }
  if (t==0){ shPrefix = 0; shNeed = KSEL; cnt2 = 0; eqc = 0; }
  for (int pass=0; pass<4; ++pass){
    const int shift = 24 - 8*pass;
    __syncthreads();
    hist[t] = 0;
    __syncthreads();
    const u32 pfx = shPrefix;
    const int need = shNeed;
    #pragma unroll
    for (int i=0;i<32;i++){
      bool act = (pass==0) || ((key[i] >> (shift+8)) == pfx);
      if (act) atomicAdd(&hist[(key[i]>>shift)&255u], 1u);
    }
    __syncthreads();
    // parallel suffix scan: sscan[t] = sum_{j>=t} hist[j]
    sscan[t] = hist[t];
    __syncthreads();
    for (int off=1; off<256; off<<=1){
      const u32 v = (t+off < 256) ? sscan[t+off] : 0u;
      __syncthreads();
      sscan[t] += v;
      __syncthreads();
    }
    const u32 un = (u32)need;
    const u32 s_t  = sscan[t];
    const u32 s_t1 = (t<255) ? sscan[t+1] : 0u;
    if (s_t >= un && s_t1 < un){
      shPrefix = (pfx<<8) | (u32)t;
      shNeed = need - (int)s_t1;
    }
  }
  __syncthreads();
  const u32 T = shPrefix; const int needEq = shNeed;
  #pragma unroll
  for (int i=0;i<32;i++){
    const int s = t + 256*i;
    if (key[i] > T){ u32 p = atomicAdd(&cnt2,1u); tidx[b*KSEL + p] = s; }
    else if (key[i] == T){ u32 e = atomicAdd(&eqc,1u); if (e < 256u) eqlist[e] = s; }
  }
  __syncthreads();
  if (t==0){
    int n = (int)eqc; if (n > 256) n = 256;
    const int bpos = (int)cnt2;
    for (int j=0;j<needEq && j<n;j++){
      int mi = j;
      for (int k2=j+1;k2<n;k2++) if (eqlist[k2] < eqlist[mi]) mi = k2;
      int tmp = eqlist[j]; eqlist[j]=eqlist[mi]; eqlist[mi]=tmp;
      tidx[b*KSEL + bpos + j] = eqlist[j];
    }
  }
}

// ---------------- fused q GEMM (blocks 0..255) + kv GEMM (blocks 256..767) ----------------
// qgemm first: gen-1 pairs 1 qgemm + 1 kv per CU (r19, best measured).
// kv role: deferred out-store (r17), now nontemporal (out is write-once;
// keeps L2 capacity for the x-read and W-glds streams).
__global__ __launch_bounds__(256,2) void kvq_kernel(const float* __restrict__ x,
                                                    const u16* __restrict__ wkv,
                                                    const u16* __restrict__ wq,
                                                    const int* __restrict__ tidx,
                                                    u16* __restrict__ K1, u16* __restrict__ K2, u16* __restrict__ V,
                                                    u16* __restrict__ Q1, u16* __restrict__ Q2,
                                                    float* __restrict__ out){
  __shared__ __align__(16) char smem[81920];
  const int tid = threadIdx.x;
  const int w = tid>>6, lane = tid&63, lo4 = lane&15, hi = lane>>4;

  if (blockIdx.x >= 256){
    // ================= kv role =================
    char* lA0 = smem;            // 2 x 16KB
    char* lB0 = smem + 32768;    // 2 x 24KB
    const long row0 = (long)(blockIdx.x - 256) * 128;
    const int srow8 = tid>>4;   // 0..15
    const int cseg  = tid&15;   // 0..15
    const float* xp = x   + (row0 + srow8)*1024 + cseg*4;
    float*       op = out + (row0 + srow8)*1024 + cseg*4;
    f32x4_t acc[12][2];
    #pragma unroll
    for (int i=0;i<12;i++){ acc[i][0]=(f32x4_t){0,0,0,0}; acc[i][1]=(f32x4_t){0,0,0,0}; }
    f32x4_t f[8], fp[8];

    auto LOADX = [&](int k0){
      #pragma unroll
      for (int i=0;i<8;i++) f[i] = *(const f32x4_t*)(xp + k0 + i*16*1024);
    };
    auto OUTSTORE = [&](int k0){     // deferred nontemporal out-store of the PREVIOUS tile
      #pragma unroll
      for (int i=0;i<8;i++)
        __builtin_nontemporal_store(fp[i], (f32x4_t*)(op + k0 + i*16*1024));
    };
    auto LDSWRITE = [&](int buf){    // bf16 pack + swizzled LDS write from f[]
      #pragma unroll
      for (int i=0;i<8;i++){
        const u32 row = (u32)(srow8 + i*16);
        u32 byte = row*128u + (u32)cseg*8u;
        byte ^= (row&7u)<<4;
        uint2 p; p.x = pkbf(f[i][0], f[i][1]); p.y = pkbf(f[i][2], f[i][3]);
        *(uint2*)(lA0 + buf*16384 + byte) = p;
      }
    };
    auto SAVEF = [&](){
      #pragma unroll
      for (int i=0;i<8;i++) fp[i] = f[i];
    };
    auto STAGEB = [&](int buf, int k0){
      #pragma unroll
      for (int ii=0; ii<6; ++ii){
        const int inst = w*6 + ii;
        const u32 L = (u32)inst*1024u + (u32)lane*16u;
        const u32 n = L>>7, off = L&127u;
        const char* src = (const char*)wkv + (size_t)n*2048 + (size_t)k0*2 + (off ^ ((n&7u)<<4));
        gl_lds16(src, lB0 + buf*24576 + (size_t)inst*1024);
      }
    };

    LOADX(0); STAGEB(0, 0); LDSWRITE(0); SAVEF();
    __syncthreads();

    for (int t=0; t<16; ++t){
      const int cur = t&1, nxt = cur^1;
      OUTSTORE(t*64);                             // store tile t (loaded last iter) early
      if (t < 15){ LOADX((t+1)*64); STAGEB(nxt, (t+1)*64); }
      #pragma unroll
      for (int kk=0;kk<2;kk++){
        bf16x8_t xf[2];
        #pragma unroll
        for (int ns=0;ns<2;ns++){
          const int s = w*32 + ns*16 + lo4;
          u32 byte = ((u32)s<<7) + ((u32)kk<<6) + ((u32)hi<<4); byte ^= ((u32)(s&7))<<4;
          xf[ns] = *(const bf16x8_t*)(lA0 + cur*16384 + byte);
        }
        #pragma unroll
        for (int ms=0;ms<12;ms++){
          const int e = ms*16 + lo4;
          u32 byte = ((u32)e<<7) + ((u32)kk<<6) + ((u32)hi<<4); byte ^= ((u32)(e&7))<<4;
          const bf16x8_t wf = *(const bf16x8_t*)(lB0 + cur*24576 + byte);
          acc[ms][0] = mfma16(wf, xf[0], acc[ms][0]);
          acc[ms][1] = mfma16(wf, xf[1], acc[ms][1]);
        }
      }
      if (t < 15){ LDSWRITE(nxt); SAVEF(); }
      __syncthreads();
    }

    #pragma unroll
    for (int ms=0;ms<12;ms++){
      const int e0 = ms*16 + 4*hi;
      const int arr = e0>>6, eh = e0&63;
      u16* basep = arr==0 ? K1 : (arr==1 ? K2 : V);
      #pragma unroll
      for (int ns=0;ns<2;ns++){
        const long srow = row0 + w*32 + ns*16 + lo4;
        ushort4 v;
        v.x = f2bf(acc[ms][ns][0]); v.y = f2bf(acc[ms][ns][1]);
        v.z = f2bf(acc[ms][ns][2]); v.w = f2bf(acc[ms][ns][3]);
        *(ushort4*)(basep + srow*64 + eh) = v;
      }
    }
  } else {
    // ================= qgemm role (blocks 0..255, dispatched first) =================
    u16* lW   = (u16*)smem;              // 16KB
    u16* lX   = (u16*)(smem + 16384);    // 4KB
    int* rows = (int*)(smem + 20480);    // 128B
    const int bq = blockIdx.x;
    const int b = bq >> 5, q0 = (bq & 31) * 32;
    if (tid < 32) rows[tid] = tidx[b*KSEL + q0 + tid];
    __syncthreads();
    const int sq = tid>>3, qt8 = tid&7;
    const float* xp = x + ((long)b*S_ + rows[sq])*1024 + qt8*8;
    f32x4_t acc[2][2];
    #pragma unroll
    for (int i=0;i<2;i++){ acc[i][0]=(f32x4_t){0,0,0,0}; acc[i][1]=(f32x4_t){0,0,0,0}; }

    for (int k0=0;k0<1024;k0+=64){
      __syncthreads();
      f32x4_t f0 = *(const f32x4_t*)(xp + k0);
      f32x4_t f1 = *(const f32x4_t*)(xp + k0 + 4);
      {
        const u32 byte = ((u32)sq<<7) + ((u32)(qt8 ^ (sq&7))<<4);
        *(u32x4_t*)((char*)lX + byte) =
          (u32x4_t){pkbf(f0[0],f0[1]), pkbf(f0[2],f0[3]), pkbf(f1[0],f1[1]), pkbf(f1[2],f1[3])};
      }
      #pragma unroll
      for (int ii=0; ii<4; ++ii){
        const int inst = w*4 + ii;
        const u32 L = (u32)inst*1024u + (u32)lane*16u;
        const u32 n = L>>7, off = L&127u;
        const char* src = (const char*)wq + (size_t)n*2048 + (size_t)k0*2 + (off ^ ((n&7u)<<4));
        gl_lds16(src, (char*)lW + (size_t)inst*1024);
      }
      __syncthreads();
      #pragma unroll
      for (int kk=0;kk<2;kk++){
        bf16x8_t xf[2];
        #pragma unroll
        for (int ns=0;ns<2;ns++){
          const int s = ns*16 + lo4;
          u32 byte = ((u32)s<<7) + ((u32)kk<<6) + ((u32)hi<<4); byte ^= ((u32)(s&7))<<4;
          xf[ns] = *(const bf16x8_t*)((const char*)lX + byte);
        }
        #pragma unroll
        for (int ms=0;ms<2;ms++){
          const int e = w*32 + ms*16 + lo4;
          u32 byte = ((u32)e<<7) + ((u32)kk<<6) + ((u32)hi<<4); byte ^= ((u32)(e&7))<<4;
          const bf16x8_t wf = *(const bf16x8_t*)((const char*)lW + byte);
          acc[ms][0] = mfma16(wf, xf[0], acc[ms][0]);
          acc[ms][1] = mfma16(wf, xf[1], acc[ms][1]);
        }
      }
    }
    #pragma unroll
    for (int ms=0;ms<2;ms++){
      const int e0 = w*32 + ms*16 + 4*hi;
      const int arr = e0>>6, eh = e0&63;
      u16* basep = arr ? Q2 : Q1;
      #pragma unroll
      for (int ns=0;ns<2;ns++){
        const int qg = q0 + ns*16 + lo4;
        ushort4 v;
        v.x = f2bf(acc[ms][ns][0]); v.y = f2bf(acc[ms][ns][1]);
        v.z = f2bf(acc[ms][ns][2]); v.w = f2bf(acc[ms][ns][3]);
        *(ushort4*)(basep + ((long)b*KSEL + qg)*64 + eh) = v;
      }
    }
  }
}

// ---------------- flash attention (dual head, swapped QK^T, S split 8, defer-max) ----------------
// T14 on V (r20) + double-buffered K tiles (r21): all staging issued during
// the prior compute phase, draining for free at barriers.
__global__ __launch_bounds__(256,2) void attn_kernel(
    const u16* __restrict__ Q1g, const u16* __restrict__ Q2g,
    const u16* __restrict__ K1g, const u16* __restrict__ K2g,
    const u16* __restrict__ Vg,  u16* __restrict__ pst)
{
  __shared__ __align__(16) u16 lK1[2][64*64];
  __shared__ __align__(16) u16 lK2[2][64*64];
  __shared__ __align__(16) u16 lVT[64*64];
  const int tid = threadIdx.x;
  const int w = tid>>6, lane = tid&63;
  const int lo5 = lane&31, hi = lane>>5;
  const int b  = blockIdx.x>>6;
  const int qt = (blockIdx.x>>3)&7;
  const int c  = blockIdx.x&7;
  const int qw = qt*4 + w;
  const int qg = qw*32 + lo5;

  u32x4_t qf[2][4];
  {
    const u16* q1p = Q1g + ((long)b*KSEL + qg)*64;
    const u16* q2p = Q2g + ((long)b*KSEL + qg)*64;
    #pragma unroll
    for (int ks=0;ks<4;ks++){
      qf[0][ks] = *(const u32x4_t*)(q1p + ks*16 + hi*8);
      qf[1][ks] = *(const u32x4_t*)(q2p + ks*16 + hi*8);
    }
  }
  f32x16_t O00 = zero16(), O01 = zero16(), O10 = zero16(), O11 = zero16();
  float m0v = -INFINITY, m1v = -INFINITY, l0v = 0.f, l1v = 0.f;
  const int vkey2 = (tid&31)*2, vdg8 = tid>>5;   // key pair + d octet

  auto KSTAGE = [&](int it, int buf){
    const int s0 = c*1024 + it*64;
    #pragma unroll
    for (int ii=0; ii<2; ++ii){
      const int inst = w*2 + ii;
      const u32 L = (u32)inst*1024u + (u32)lane*16u;
      const u32 r = L>>7;
      const u32 so = (r<<7) | ((L&127u) ^ ((r&7u)<<4));
      const long gb = ((long)(b*S_ + s0))*128;
      gl_lds16((const char*)K1g + gb + so, (char*)lK1[buf] + (size_t)inst*1024);
      gl_lds16((const char*)K2g + gb + so, (char*)lK2[buf] + (size_t)inst*1024);
    }
  };

  // prologue: K glds(0) into buf 0, V regs(0)
  KSTAGE(0, 0);
  u32x4_t va0, va1;
  {
    const u16* vp0 = Vg + ((long)(b*S_ + c*1024 + vkey2))*64 + vdg8*8;
    va0 = *(const u32x4_t*)(vp0);
    va1 = *(const u32x4_t*)(vp0 + 64);
  }

  for (int it=0; it<16; ++it){
    const int kbuf = it&1;
    const int s0 = c*1024 + it*64;
    __syncthreads();                               // A: K glds(it) drained (issued last compute)
    // stage V transposed (V^T[d][key]) from registers loaded last iteration
    {
      #pragma unroll
      for (int j=0;j<8;j++){
        const u32 w0 = va0[j>>1], w1 = va1[j>>1];
        const u16 v0 = (j&1) ? (u16)(w0>>16) : (u16)(w0 & 0xffffu);
        const u16 v1 = (j&1) ? (u16)(w1>>16) : (u16)(w1 & 0xffffu);
        const int d = vdg8*8 + j;
        u32 byte = ((u32)d<<7) + (u32)vkey2*2;
        byte ^= ((u32)(d&7))<<4;
        *(u32*)((char*)lVT + byte) = (u32)v0 | ((u32)v1<<16);
      }
    }
    __syncthreads();                               // B: staging visible
    // T14/T3: issue next tile's K glds (inactive buffer) + V reg loads now;
    // they ride during compute and drain at the next barrier A.
    if (it < 15){
      KSTAGE(it+1, kbuf^1);
      const u16* vpn = Vg + ((long)(b*S_ + s0 + 64 + vkey2))*64 + vdg8*8;
      va0 = *(const u32x4_t*)(vpn);
      va1 = *(const u32x4_t*)(vpn + 64);
    }
    #pragma unroll
    for (int h=0; h<2; ++h){
      const u16* lK = h ? lK2[kbuf] : lK1[kbuf];
      f32x16_t sc0 = zero16(), sc1 = zero16();   // D[key][q]: col=q, rows=keys
      #pragma unroll
      for (int ks=0; ks<4; ++ks){
        u32 byteA = (((u32)lo5)<<7) + ((u32)ks<<5) + ((u32)hi<<4);
        byteA ^= ((u32)(lo5&7))<<4;
        const bf16x8_t kf0 = *(const bf16x8_t*)((const char*)lK + byteA);
        const bf16x8_t kf1 = *(const bf16x8_t*)((const char*)lK + (byteA + 4096));
        sc0 = mfma32(kf0, bc8(qf[h][ks]), sc0);
        sc1 = mfma32(kf1, bc8(qf[h][ks]), sc1);
      }
      const float mref = h ? m1v : m0v;
      float tmax = -INFINITY;
      #pragma unroll
      for (int i=0;i<16;i++){ tmax = fmaxf(tmax, sc0[i]); tmax = fmaxf(tmax, sc1[i]); }
      tmax = fmaxf(tmax, __shfl_xor(tmax, 32, 64));
      // defer-max: only advance m when tile max exceeds m_old + 8 (P <= e^8)
      const bool upd = (tmax > mref + 8.f);
      const float mnew = upd ? tmax : mref;
      const float ce = upd ? __expf(mref - mnew) : 1.f;
      float lsum = 0.f;
      #pragma unroll
      for (int i=0;i<16;i++){
        sc0[i] = __expf(sc0[i]-mnew); lsum += sc0[i];
        sc1[i] = __expf(sc1[i]-mnew); lsum += sc1[i];
      }
      lsum += __shfl_xor(lsum, 32, 64);
      if (h==0){ l0v = upd ? l0v*ce + lsum : l0v + lsum; m0v = mnew; }
      else     { l1v = upd ? l1v*ce + lsum : l1v + lsum; m1v = mnew; }
      f32x16_t &Oa = h ? O10 : O00;
      f32x16_t &Ob = h ? O11 : O01;
      if (upd){
        #pragma unroll
        for (int i=0;i<16;i++){ Oa[i] *= ce; Ob[i] *= ce; }
      }
      #pragma unroll
      for (int kb=0; kb<2; ++kb){
        const f32x16_t &s = kb ? sc1 : sc0;
        u32 pk[8], sx[8];
        #pragma unroll
        for (int i=0;i<8;i++) pk[i] = pkbf(s[2*i], s[2*i+1]);
        #pragma unroll
        for (int i=0;i<8;i++) sx[i] = (u32)__shfl_xor((int)pk[i], 32, 64);
        #pragma unroll
        for (int dd=0; dd<2; ++dd){
          const u32 w0 = hi ? sx[4*dd+2] : pk[4*dd];
          const u32 w1 = hi ? sx[4*dd+3] : pk[4*dd+1];
          const u32 w2 = hi ? pk[4*dd+2] : sx[4*dd];
          const u32 w3 = hi ? pk[4*dd+3] : sx[4*dd+1];
          const bf16x8_t pf = bc8((u32x4_t){w0,w1,w2,w3});
          const int ksG = kb*2 + dd;
          u32 byteV = (((u32)lo5)<<7) + ((u32)ksG<<5) + ((u32)hi<<4);
          byteV ^= ((u32)(lo5&7))<<4;
          const bf16x8_t vf0 = *(const bf16x8_t*)((const char*)lVT + byteV);
          const bf16x8_t vf1 = *(const bf16x8_t*)((const char*)lVT + (byteV + 4096));
          Oa = mfma32(vf0, pf, Oa);
          Ob = mfma32(vf1, pf, Ob);
        }
      }
    }
  }
  const long rec = (((long)b*32 + qw)*8 + c)*2;
  u16* p0 = pst + rec*PREC;
  u16* p1 = p0 + PREC;
  #pragma unroll
  for (int r2=0;r2<16;r2++){
    p0[(   r2)*64 + lane] = f2bf(O00[r2]);
    p0[(16+r2)*64 + lane] = f2bf(O01[r2]);
    p1[(   r2)*64 + lane] = f2bf(O10[r2]);
    p1[(16+r2)*64 + lane] = f2bf(O11[r2]);
  }
  ((float*)(p0+2048))[lane] = m0v; ((float*)(p0+2176))[lane] = l0v;
  ((float*)(p1+2048))[lane] = m1v; ((float*)(p1+2176))[lane] = l1v;
}

// ---------------- combine chunks + RMS + W_out GEMM + merge + scatter ----------------
__global__ __launch_bounds__(64,1) void combine_kernel(
    const u16* __restrict__ pst, const int* __restrict__ tidx,
    const float* __restrict__ x, const float* __restrict__ rmsw,
    const float* __restrict__ lamp, const float* __restrict__ gatep,
    const u16* __restrict__ wo, const float* __restrict__ bo,
    float* __restrict__ out)
{
  const int lane = threadIdx.x, lo5 = lane&31, hi = lane>>5;
  const int sb = blockIdx.x & 3;
  const int qw = (blockIdx.x>>2) & 31;
  const int b  = blockIdx.x >> 7;
  const float lam = 1.f/(1.f + __expf(-lamp[0]));
  const float g = gatep[0];
  const long rec0 = ((long)b*32 + qw)*16;
  float att[2][16];
  #pragma unroll
  for (int h=0; h<2; ++h){
    const u16* ph = pst + (rec0 + h)*PREC;
    float mc[8], lc[8];
    float mm = -INFINITY;
    #pragma unroll
    for (int cc=0;cc<8;cc++){
      const u16* pc = ph + (size_t)cc*2*PREC;
      mc[cc] = ((const float*)(pc+2048))[lane];
      lc[cc] = ((const float*)(pc+2176))[lane];
      mm = fmaxf(mm, mc[cc]);
    }
    float ef[8]; float L = 0.f;
    #pragma unroll
    for (int cc=0;cc<8;cc++){ ef[cc] = __expf(mc[cc]-mm); L += lc[cc]*ef[cc]; }
    const float invL = 1.f/L;
    #pragma unroll
    for (int dB=0; dB<2; ++dB){
      #pragma unroll
      for (int r=0;r<16;r++){
        float o = 0.f;
        #pragma unroll
        for (int cc=0;cc<8;cc++)
          o += ef[cc]*bf2f(ph[(size_t)cc*2*PREC + (dB*16+r)*64 + lane]);
        o *= invL;
        if (h==0) att[dB][r] = o; else att[dB][r] -= lam*o;
      }
    }
  }
  float ss = 0.f;
  #pragma unroll
  for (int dB=0;dB<2;dB++)
    #pragma unroll
    for (int r=0;r<16;r++) ss += att[dB][r]*att[dB][r];
  ss += __shfl_xor(ss, 32, 64);
  const float inv = rsqrtf(ss*(1.0f/64.0f) + 1e-6f);
  #pragma unroll
  for (int dB=0;dB<2;dB++){
    #pragma unroll
    for (int rq=0;rq<4;rq++){
      const f32x4_t wv = *(const f32x4_t*)(rmsw + dB*32 + 8*rq + 4*hi);
      #pragma unroll
      for (int j=0;j<4;j++) att[dB][4*rq+j] *= inv*wv[j];
    }
  }
  bf16x8_t hf[4];
  #pragma unroll
  for (int dB=0;dB<2;dB++){
    u32 pk[8], sx[8];
    #pragma unroll
    for (int i=0;i<8;i++) pk[i] = pkbf(att[dB][2*i], att[dB][2*i+1]);
    #pragma unroll
    for (int i=0;i<8;i++) sx[i] = (u32)__shfl_xor((int)pk[i], 32, 64);
    #pragma unroll
    for (int dd=0; dd<2; ++dd){
      const u32 w0 = hi ? sx[4*dd+2] : pk[4*dd];
      const u32 w1 = hi ? sx[4*dd+3] : pk[4*dd+1];
      const u32 w2 = hi ? pk[4*dd+2] : sx[4*dd];
      const u32 w3 = hi ? pk[4*dd+3] : sx[4*dd+1];
      hf[dB*2+dd] = bc8((u32x4_t){w0,w1,w2,w3});
    }
  }
  const int srow = tidx[b*KSEL + qw*32 + lo5];
  const float* xr  = x   + ((long)b*S_ + srow)*1024;
  float*       orr = out + ((long)b*S_ + srow)*1024;
  for (int st=sb*8; st<sb*8+8; ++st){
    f32x16_t acc = zero16();
    #pragma unroll
    for (int ks=0;ks<4;ks++){
      const u32x4_t wq4 = *(const u32x4_t*)(wo + ((long)(st*32 + lo5))*64 + ks*16 + hi*8);
      acc = mfma32(bc8(wq4), hf[ks], acc);
    }
    #pragma unroll
    for (int rq=0;rq<4;rq++){
      const int d0 = st*32 + 8*rq + 4*hi;
      const f32x4_t bo4 = *(const f32x4_t*)(bo + d0);
      const f32x4_t xv  = *(const f32x4_t*)(xr + d0);
      f32x4_t mg;
      #pragma unroll
      for (int j=0;j<4;j++){
        const float y = acc[4*rq+j] + bo4[j];
        mg[j] = g*y + (1.f-g)*xv[j];
      }
      *(f32x4_t*)(orr + d0) = mg;
    }
  }
}

// ---------------- launcher ----------------
extern "C" void kernel_launch(void* const* d_in, const int* in_sizes, int n_in,
                              void* d_out, int out_size, void* d_ws, size_t ws_size,
                              hipStream_t stream) {
  (void)in_sizes; (void)n_in; (void)out_size; (void)ws_size;
  const float* x    = (const float*)d_in[0];
  const float* imp  = (const float*)d_in[1];
  const float* wq   = (const float*)d_in[2];
  const float* wkv  = (const float*)d_in[3];
  const float* lamp = (const float*)d_in[4];
  const float* rmsw = (const float*)d_in[5];
  const float* gate = (const float*)d_in[6];
  const float* wo   = (const float*)d_in[7];
  const float* bo   = (const float*)d_in[8];
  float* out = (float*)d_out;
  char* ws = (char*)d_ws;
  u16* Wq   = (u16*)(ws + OFF_WQ);
  u16* Wkv  = (u16*)(ws + OFF_WKV);
  u16* Wo   = (u16*)(ws + OFF_WO);
  int* Tidx = (int*)(ws + OFF_TIDX);
  u16* K1   = (u16*)(ws + OFF_K1);
  u16* K2   = (u16*)(ws + OFF_K2);
  u16* V    = (u16*)(ws + OFF_V);
  u16* Q1   = (u16*)(ws + OFF_Q1);
  u16* Q2   = (u16*)(ws + OFF_Q2);
  u16* Pst  = (u16*)(ws + OFF_PST);

  preptopk_kernel<<<776, 256, 0, stream>>>(wq, wkv, wo, imp, Wq, Wkv, Wo, Tidx);
  kvq_kernel<<<768, 256, 0, stream>>>(x, Wkv, Wq, Tidx, K1, K2, V, Q1, Q2, out);
  attn_kernel<<<512, 256, 0, stream>>>(Q1, Q2, K1, K2, V, Pst);
  combine_kernel<<<1024, 64, 0, stream>>>(Pst, Tidx, x, rmsw, lamp, gate, Wo, bo, out);
}